// Round 6
// baseline (211.038 us; speedup 1.0000x reference)
//
#include <hip/hip_runtime.h>
#include <math.h>

// TD(lambda) backward scan as a parallel suffix scan of affine maps.
// ret[t] = b[t] + a[t]*ret[t+1],  a[t]=g*(1-d)*lam[t],  b[t]=r[t]+g*(1-d)*(1-lam[t])*v[t+1]
//
// R5 (REVERTED): CU-temporal r/d loads -> 87us. nt is the fast load path.
// R6 (NEUTRAL): 2 rows/block; dur invariant -> throughput-clamped.
// R7 (PARTIAL): C=4 coalesced halves; WRITE exact 65.5MB; dur ~63us.
// R8 (REVERTED): sc0/sc1 loads: FETCH bit-identical (MALL hint-independent),
//   read path 37% slower.
// R9 (WIN, small): temporal stores 63.4->60.3us. WRITE unchanged (65.5MB) ->
//   MALL not steerable from store side either; temporal is just the faster
//   store path. Kept.
// R10: last slow-path traffic eliminated. values (67MB, 1/3 of reads) was
//   CU-temporal because the misaligned window needed 2 overlapping 16B loads
//   (L1 dedup). Replace with ONE aligned nt dwordx4 per thread at vp-s
//   (wave-contiguous 1KB, zero overlap/waste) + neighbor-register recombine:
//   vv[i] = (s+i<4) ? w[s+i] : shfl_down(w,1)[s+i-4]; lane 63 patches its
//   tail with <=3 guarded scalar loads. s=(row+1)&3 is row-uniform -> the
//   recombine branch is uniform. Entire 201MB read stream now on the nt path.

#define EPSV 1e-8f

typedef float f32x4 __attribute__((ext_vector_type(4)));

__global__ void precompute_lambda_kernel(const float* __restrict__ raw_gamma,
                                         const float* __restrict__ raw_lambd,
                                         float* __restrict__ lam, int S) {
    int t = blockIdx.x * blockDim.x + threadIdx.x;
    if (t < S) lam[t] = fmaxf(tanhf(raw_lambd[t]), EPSV);
    if (t == S) lam[S] = fmaxf(tanhf(raw_gamma[0]), EPSV);  // gamma stashed at lam[S]
}

// Pure-nt misaligned 4-float load: one aligned nt dwordx4 at vp-s per thread
// (wave-contiguous, no inter-instruction line overlap), spill-over floats
// recovered from the next lane's registers via shfl_down; lane 63 patches
// its tail with guarded scalar loads. s must be wave-uniform.
__device__ __forceinline__ void load_v4_nt(const float* __restrict__ vp,
                                           int s, int lane,
                                           const float* __restrict__ hi,
                                           float vv[4]) {
    const float* base = vp - s;                       // 16B-aligned
    f32x4 w = __builtin_nontemporal_load(reinterpret_cast<const f32x4*>(base));
    if (s == 0) { vv[0]=w[0]; vv[1]=w[1]; vv[2]=w[2]; vv[3]=w[3]; return; }
    float wn0 = __shfl_down(w[0], 1);                 // next lane's base[4..7)
    float wn1 = __shfl_down(w[1], 1);
    float wn2 = __shfl_down(w[2], 1);
    if (lane == 63) {                                 // no next lane in-wave
        const float* p = base + 4;
        wn0 = (p + 0 < hi) ? p[0] : 0.0f;             // guards match usage:
        wn1 = (p + 1 < hi) ? p[1] : 0.0f;             // wn[j] only used for j<s
        wn2 = (p + 2 < hi) ? p[2] : 0.0f;
    }
    if (s == 1)      { vv[0]=w[1]; vv[1]=w[2]; vv[2]=w[3]; vv[3]=wn0; }
    else if (s == 2) { vv[0]=w[2]; vv[1]=w[3]; vv[2]=wn0; vv[3]=wn1; }
    else             { vv[0]=w[3]; vv[1]=wn0; vv[2]=wn1; vv[3]=wn2; }
}

// Block-wide suffix scan over 256 per-thread affine maps (A,Bc).
// Outputs: (Af,Bf) = exclusive suffix map of chunks tid+1..255; (GA,GB) =
// full block aggregate. Contains one __syncthreads.
__device__ __forceinline__ void block_suffix_scan(
    float A, float Bc, float* aggAs, float* aggBs, int lane, int wave,
    float& Af, float& Bf, float& GA, float& GB)
{
    float Ai = A, Bi = Bc;
    #pragma unroll
    for (int off = 1; off < 64; off <<= 1) {
        float Ao = __shfl_down(Ai, off);
        float Bo = __shfl_down(Bi, off);
        if (lane + off < 64) { Bi = fmaf(Ai, Bo, Bi); Ai = Ai * Ao; }
    }
    float Ae = __shfl_down(Ai, 1);
    float Be = __shfl_down(Bi, 1);
    if (lane == 63) { Ae = 1.0f; Be = 0.0f; }

    if (lane == 0) { aggAs[wave] = Ai; aggBs[wave] = Bi; }
    __syncthreads();
    float TA = 1.0f, TB = 0.0f;          // tail = agg[wave+1] o ... o agg[3]
    for (int w2 = wave + 1; w2 < 4; ++w2) {
        TB = fmaf(TA, aggBs[w2], TB);
        TA = TA * aggAs[w2];
    }
    Af = Ae * TA;
    Bf = fmaf(Ae, TB, Be);
    GA = 1.0f; GB = 0.0f;                // full aggregate agg[0] o ... o agg[3]
    #pragma unroll
    for (int w2 = 0; w2 < 4; ++w2) {
        GB = fmaf(GA, aggBs[w2], GB);
        GA = GA * aggAs[w2];
    }
}

__global__ __launch_bounds__(256) void lamret_kernel(
    const float* __restrict__ values,    // [B, S+1]
    const float* __restrict__ rewards,   // [B, S]
    const float* __restrict__ dones,     // [B, S]
    const float* __restrict__ raw_gamma, // [1]   (fallback path)
    const float* __restrict__ raw_lambd, // [S]   (fallback path)
    const float* __restrict__ lam_pre,   // [S+1] precomputed (or nullptr)
    float* __restrict__ out,             // [B, S]
    int S, long vtotal)
{
    __shared__ float aggA[2][4], aggB[2][4];

    const int row  = blockIdx.x;
    const int tid  = threadIdx.x;
    const int lane = tid & 63;
    const int wave = tid >> 6;

    const float* __restrict__ rrow = rewards + (size_t)row * S;
    const float* __restrict__ drow = dones   + (size_t)row * S;
    const float* __restrict__ vrow = values  + (size_t)row * (S + 1);
    float* __restrict__ orow = out + (size_t)row * S;

    float gamma;
    if (lam_pre) gamma = lam_pre[S];
    else         gamma = fmaxf(tanhf(raw_gamma[0]), EPSV);

    const float vlast = vrow[S];   // uniform scalar load, issued early

    if (S == 2048) {
        // ---------------- fast path: C=4 chunks over two halves ----------------
        constexpr int C = 4;
        const int HALF = 1024;
        const int t1 = tid * C;          // half1 chunk start
        const int t2 = HALF + tid * C;   // half2 chunk start

        // ---- r/d: nontemporal loads (fast path, zero overlap)
        f32x4 r1 = __builtin_nontemporal_load(reinterpret_cast<const f32x4*>(rrow + t1));
        f32x4 r2 = __builtin_nontemporal_load(reinterpret_cast<const f32x4*>(rrow + t2));
        f32x4 d1 = __builtin_nontemporal_load(reinterpret_cast<const f32x4*>(drow + t1));
        f32x4 d2 = __builtin_nontemporal_load(reinterpret_cast<const f32x4*>(drow + t2));

        // ---- v: pure-nt aligned load + register recombine (s row-uniform)
        const int s = (int)(((uintptr_t)(vrow + 1) >> 2) & 3);
        float vv1[C], vv2[C];
        load_v4_nt(vrow + t1 + 1, s, lane, values + vtotal, vv1);
        load_v4_nt(vrow + t2 + 1, s, lane, values + vtotal, vv2);

        float lm1[C], lm2[C];
        if (lam_pre) {
            f32x4 l1 = *reinterpret_cast<const f32x4*>(lam_pre + t1);
            f32x4 l2 = *reinterpret_cast<const f32x4*>(lam_pre + t2);
            #pragma unroll
            for (int i = 0; i < C; ++i) { lm1[i] = l1[i]; lm2[i] = l2[i]; }
        } else {
            #pragma unroll
            for (int i = 0; i < C; ++i) {
                lm1[i] = fmaxf(tanhf(raw_lambd[t1 + i]), EPSV);
                lm2[i] = fmaxf(tanhf(raw_lambd[t2 + i]), EPSV);
            }
        }

        // ---- per-chunk affine coefficients
        float a1[C], b1[C], a2[C], b2[C];
        #pragma unroll
        for (int i = 0; i < C; ++i) {
            float g1d = gamma * (1.0f - d1[i]);
            a1[i] = g1d * lm1[i];
            b1[i] = fmaf(g1d * (1.0f - lm1[i]), vv1[i], r1[i]);
        }
        #pragma unroll
        for (int i = 0; i < C; ++i) {
            float g1d = gamma * (1.0f - d2[i]);
            a2[i] = g1d * lm2[i];
            b2[i] = fmaf(g1d * (1.0f - lm2[i]), vv2[i], r2[i]);
        }

        // ---- local compositions
        float A1 = 1.0f, B1 = 0.0f, A2 = 1.0f, B2 = 0.0f;
        #pragma unroll
        for (int i = C - 1; i >= 0; --i) {
            B1 = fmaf(a1[i], B1, b1[i]);  A1 = a1[i] * A1;
            B2 = fmaf(a2[i], B2, b2[i]);  A2 = a2[i] * A2;
        }

        // ---- scan half2 (time-later), get carry + full-half2 aggregate
        float Af2, Bf2, G2A, G2B;
        block_suffix_scan(A2, B2, aggA[1], aggB[1], lane, wave, Af2, Bf2, G2A, G2B);
        float x2 = fmaf(Af2, vlast, Bf2);       // carry entering half2 chunk

        // ---- scan half1, seeded with G2(vlast)
        float Af1, Bf1, G1A, G1B;
        block_suffix_scan(A1, B1, aggA[0], aggB[0], lane, wave, Af1, Bf1, G1A, G1B);
        float xg = fmaf(G2A, vlast, G2B);       // value entering half2
        float x1 = fmaf(Af1, xg, Bf1);          // carry entering half1 chunk

        // ---- backward apply + temporal stores (R9: faster store path)
        f32x4 o1, o2;
        #pragma unroll
        for (int i = C - 1; i >= 0; --i) {
            x2 = fmaf(a2[i], x2, b2[i]);  o2[i] = x2;
            x1 = fmaf(a1[i], x1, b1[i]);  o1[i] = x1;
        }
        *reinterpret_cast<f32x4*>(orow + t1) = o1;
        *reinterpret_cast<f32x4*>(orow + t2) = o2;
    } else {
        // ---------------- generic path: C=8 scalar, single scan ----------------
        constexpr int C = 8;
        const int t0 = tid * C;
        float a[C], b[C];
        #pragma unroll
        for (int i = 0; i < C; ++i) {
            int t = t0 + i;
            if (t < S) {
                float lmv = lam_pre ? lam_pre[t] : fmaxf(tanhf(raw_lambd[t]), EPSV);
                float g1d = gamma * (1.0f - drow[t]);
                a[i] = g1d * lmv;
                b[i] = fmaf(g1d * (1.0f - lmv), vrow[t + 1], rrow[t]);
            } else { a[i] = 1.0f; b[i] = 0.0f; }
        }
        float A = 1.0f, Bc = 0.0f;
        #pragma unroll
        for (int i = C - 1; i >= 0; --i) {
            Bc = fmaf(a[i], Bc, b[i]);
            A  = a[i] * A;
        }
        float Af, Bf, GA, GB;
        block_suffix_scan(A, Bc, aggA[0], aggB[0], lane, wave, Af, Bf, GA, GB);
        float x = fmaf(Af, vlast, Bf);
        #pragma unroll
        for (int i = C - 1; i >= 0; --i) {
            x = fmaf(a[i], x, b[i]);
            if (t0 + i < S) orow[t0 + i] = x;
        }
    }
}

extern "C" void kernel_launch(void* const* d_in, const int* in_sizes, int n_in,
                              void* d_out, int out_size, void* d_ws, size_t ws_size,
                              hipStream_t stream) {
    const float* values    = (const float*)d_in[0];
    const float* rewards   = (const float*)d_in[1];
    const float* dones     = (const float*)d_in[2];
    const float* raw_gamma = (const float*)d_in[3];
    const float* raw_lambd = (const float*)d_in[4];
    float* out = (float*)d_out;

    const int S = in_sizes[4];            // raw_lambd length
    const int B = in_sizes[1] / S;        // rewards = B*S
    const long vtotal = in_sizes[0];      // B*(S+1)

    float* lam_pre = nullptr;
    if (ws_size >= (size_t)(S + 1) * sizeof(float)) {
        lam_pre = (float*)d_ws;
        int nthr = 256;
        int nblk = (S + 1 + nthr - 1) / nthr;
        precompute_lambda_kernel<<<nblk, nthr, 0, stream>>>(raw_gamma, raw_lambd, lam_pre, S);
    }

    // one block per row; 256 threads, C=4 over two 1024-step halves
    lamret_kernel<<<B, 256, 0, stream>>>(values, rewards, dones,
                                         raw_gamma, raw_lambd, lam_pre, out, S, vtotal);
}

// Round 7
// 210.140 us; speedup vs baseline: 1.0043x; 1.0043x over previous
//
#include <hip/hip_runtime.h>
#include <math.h>

// TD(lambda) backward scan as a parallel suffix scan of affine maps.
// ret[t] = b[t] + a[t]*ret[t+1],  a[t]=g*(1-d)*lam[t],  b[t]=r[t]+g*(1-d)*(1-lam[t])*v[t+1]
//
// R5 (REVERTED): CU-temporal r/d loads -> 87us. nt is the fast load path.
// R6 (NEUTRAL): 2 rows/block; dur invariant -> throughput-clamped.
// R7 (PARTIAL): C=4 coalesced halves; WRITE exact 65.5MB.
// R8 (REVERTED): sc0/sc1 loads: FETCH bit-identical, read path 37% slower.
// R9 (WIN): temporal stores 63.4->60.3us (faster store path; WRITE unchanged).
// R10 (WIN): values on pure-nt path via aligned nt dwordx4 + neighbor-register
//   recombine: 60.3->56.5us. All 201MB of reads now on the nt path.
// R11: structural simplification. The two sequential block scans (two
//   dependent 6-round ds_bpermute chains + two __syncthreads) sat on the
//   critical path between load and store phases. 512 threads x C=4 cover
//   the row in ONE coalesced slab: per thread one r/d/v/lam load, ONE wave
//   scan, ONE barrier, 8-wave tail, one store. Memory policy unchanged.

#define EPSV 1e-8f

typedef float f32x4 __attribute__((ext_vector_type(4)));

__global__ void precompute_lambda_kernel(const float* __restrict__ raw_gamma,
                                         const float* __restrict__ raw_lambd,
                                         float* __restrict__ lam, int S) {
    int t = blockIdx.x * blockDim.x + threadIdx.x;
    if (t < S) lam[t] = fmaxf(tanhf(raw_lambd[t]), EPSV);
    if (t == S) lam[S] = fmaxf(tanhf(raw_gamma[0]), EPSV);  // gamma stashed at lam[S]
}

// Pure-nt misaligned 4-float load: one aligned nt dwordx4 at vp-s per thread
// (wave-contiguous, no inter-instruction line overlap), spill-over floats
// recovered from the next lane's registers via shfl_down; lane 63 patches
// its tail with guarded scalar loads. s must be wave-uniform.
__device__ __forceinline__ void load_v4_nt(const float* __restrict__ vp,
                                           int s, int lane,
                                           const float* __restrict__ hi,
                                           float vv[4]) {
    const float* base = vp - s;                       // 16B-aligned
    f32x4 w = __builtin_nontemporal_load(reinterpret_cast<const f32x4*>(base));
    if (s == 0) { vv[0]=w[0]; vv[1]=w[1]; vv[2]=w[2]; vv[3]=w[3]; return; }
    float wn0 = __shfl_down(w[0], 1);                 // next lane's base[4..7)
    float wn1 = __shfl_down(w[1], 1);
    float wn2 = __shfl_down(w[2], 1);
    if (lane == 63) {                                 // no next lane in-wave
        const float* p = base + 4;
        wn0 = (p + 0 < hi) ? p[0] : 0.0f;             // guards match usage:
        wn1 = (p + 1 < hi) ? p[1] : 0.0f;             // wn[j] only used for j<s
        wn2 = (p + 2 < hi) ? p[2] : 0.0f;
    }
    if (s == 1)      { vv[0]=w[1]; vv[1]=w[2]; vv[2]=w[3]; vv[3]=wn0; }
    else if (s == 2) { vv[0]=w[2]; vv[1]=w[3]; vv[2]=wn0; vv[3]=wn1; }
    else             { vv[0]=w[3]; vv[1]=wn0; vv[2]=wn1; vv[3]=wn2; }
}

// Block-wide suffix scan over NW*64 per-thread affine maps (A,Bc).
// Output: (Af,Bf) = exclusive suffix map of threads tid+1..NW*64-1.
// Contains exactly one __syncthreads.
template <int NW>
__device__ __forceinline__ void block_suffix_scan(
    float A, float Bc, float* aggAs, float* aggBs, int lane, int wave,
    float& Af, float& Bf)
{
    float Ai = A, Bi = Bc;
    #pragma unroll
    for (int off = 1; off < 64; off <<= 1) {
        float Ao = __shfl_down(Ai, off);
        float Bo = __shfl_down(Bi, off);
        if (lane + off < 64) { Bi = fmaf(Ai, Bo, Bi); Ai = Ai * Ao; }
    }
    float Ae = __shfl_down(Ai, 1);
    float Be = __shfl_down(Bi, 1);
    if (lane == 63) { Ae = 1.0f; Be = 0.0f; }

    if (lane == 0) { aggAs[wave] = Ai; aggBs[wave] = Bi; }
    __syncthreads();
    float TA = 1.0f, TB = 0.0f;          // tail = agg[wave+1] o ... o agg[NW-1]
    for (int w2 = wave + 1; w2 < NW; ++w2) {
        TB = fmaf(TA, aggBs[w2], TB);
        TA = TA * aggAs[w2];
    }
    Af = Ae * TA;
    Bf = fmaf(Ae, TB, Be);
}

__global__ __launch_bounds__(512) void lamret_kernel(
    const float* __restrict__ values,    // [B, S+1]
    const float* __restrict__ rewards,   // [B, S]
    const float* __restrict__ dones,     // [B, S]
    const float* __restrict__ raw_gamma, // [1]   (fallback path)
    const float* __restrict__ raw_lambd, // [S]   (fallback path)
    const float* __restrict__ lam_pre,   // [S+1] precomputed (or nullptr)
    float* __restrict__ out,             // [B, S]
    int S, long vtotal)
{
    __shared__ float aggA[8], aggB[8];

    const int row  = blockIdx.x;
    const int tid  = threadIdx.x;
    const int lane = tid & 63;
    const int wave = tid >> 6;

    const float* __restrict__ rrow = rewards + (size_t)row * S;
    const float* __restrict__ drow = dones   + (size_t)row * S;
    const float* __restrict__ vrow = values  + (size_t)row * (S + 1);
    float* __restrict__ orow = out + (size_t)row * S;

    float gamma;
    if (lam_pre) gamma = lam_pre[S];
    else         gamma = fmaxf(tanhf(raw_gamma[0]), EPSV);

    const float vlast = vrow[S];   // uniform scalar load, issued early

    if (S == 2048) {
        // ------------- fast path: 512 threads x C=4, one coalesced slab -------------
        constexpr int C = 4;
        const int t0 = tid * C;

        // ---- r/d: nontemporal loads (fast path, zero overlap)
        f32x4 r = __builtin_nontemporal_load(reinterpret_cast<const f32x4*>(rrow + t0));
        f32x4 d = __builtin_nontemporal_load(reinterpret_cast<const f32x4*>(drow + t0));

        // ---- v: pure-nt aligned load + register recombine (s row-uniform)
        const int s = (int)(((uintptr_t)(vrow + 1) >> 2) & 3);
        float vv[C];
        load_v4_nt(vrow + t0 + 1, s, lane, values + vtotal, vv);

        // ---- lam: temporal (tiny, L2-resident broadcast)
        float lm[C];
        if (lam_pre) {
            f32x4 l = *reinterpret_cast<const f32x4*>(lam_pre + t0);
            #pragma unroll
            for (int i = 0; i < C; ++i) lm[i] = l[i];
        } else {
            #pragma unroll
            for (int i = 0; i < C; ++i) lm[i] = fmaxf(tanhf(raw_lambd[t0 + i]), EPSV);
        }

        // ---- per-chunk affine coefficients
        float a[C], b[C];
        #pragma unroll
        for (int i = 0; i < C; ++i) {
            float g1d = gamma * (1.0f - d[i]);
            a[i] = g1d * lm[i];
            b[i] = fmaf(g1d * (1.0f - lm[i]), vv[i], r[i]);
        }

        // ---- local composition
        float A = 1.0f, Bc = 0.0f;
        #pragma unroll
        for (int i = C - 1; i >= 0; --i) {
            Bc = fmaf(a[i], Bc, b[i]);
            A  = a[i] * A;
        }

        // ---- single block scan (one barrier)
        float Af, Bf;
        block_suffix_scan<8>(A, Bc, aggA, aggB, lane, wave, Af, Bf);
        float x = fmaf(Af, vlast, Bf);        // carry entering this chunk

        // ---- backward apply + temporal store (R9: faster store path)
        f32x4 o;
        #pragma unroll
        for (int i = C - 1; i >= 0; --i) {
            x = fmaf(a[i], x, b[i]);
            o[i] = x;
        }
        *reinterpret_cast<f32x4*>(orow + t0) = o;
    } else {
        // ------------- generic path: C=8 scalar, single scan (S <= 4096) -------------
        constexpr int C = 8;
        const int t0 = tid * C;
        float a[C], b[C];
        #pragma unroll
        for (int i = 0; i < C; ++i) {
            int t = t0 + i;
            if (t < S) {
                float lmv = lam_pre ? lam_pre[t] : fmaxf(tanhf(raw_lambd[t]), EPSV);
                float g1d = gamma * (1.0f - drow[t]);
                a[i] = g1d * lmv;
                b[i] = fmaf(g1d * (1.0f - lmv), vrow[t + 1], rrow[t]);
            } else { a[i] = 1.0f; b[i] = 0.0f; }
        }
        float A = 1.0f, Bc = 0.0f;
        #pragma unroll
        for (int i = C - 1; i >= 0; --i) {
            Bc = fmaf(a[i], Bc, b[i]);
            A  = a[i] * A;
        }
        float Af, Bf;
        block_suffix_scan<8>(A, Bc, aggA, aggB, lane, wave, Af, Bf);
        float x = fmaf(Af, vlast, Bf);
        #pragma unroll
        for (int i = C - 1; i >= 0; --i) {
            x = fmaf(a[i], x, b[i]);
            if (t0 + i < S) orow[t0 + i] = x;
        }
    }
}

extern "C" void kernel_launch(void* const* d_in, const int* in_sizes, int n_in,
                              void* d_out, int out_size, void* d_ws, size_t ws_size,
                              hipStream_t stream) {
    const float* values    = (const float*)d_in[0];
    const float* rewards   = (const float*)d_in[1];
    const float* dones     = (const float*)d_in[2];
    const float* raw_gamma = (const float*)d_in[3];
    const float* raw_lambd = (const float*)d_in[4];
    float* out = (float*)d_out;

    const int S = in_sizes[4];            // raw_lambd length
    const int B = in_sizes[1] / S;        // rewards = B*S
    const long vtotal = in_sizes[0];      // B*(S+1)

    float* lam_pre = nullptr;
    if (ws_size >= (size_t)(S + 1) * sizeof(float)) {
        lam_pre = (float*)d_ws;
        int nthr = 256;
        int nblk = (S + 1 + nthr - 1) / nthr;
        precompute_lambda_kernel<<<nblk, nthr, 0, stream>>>(raw_gamma, raw_lambd, lam_pre, S);
    }

    // one block per row; 512 threads * 4 steps = 2048 timesteps per block
    lamret_kernel<<<B, 512, 0, stream>>>(values, rewards, dones,
                                         raw_gamma, raw_lambd, lam_pre, out, S, vtotal);
}

// Round 8
// 209.218 us; speedup vs baseline: 1.0087x; 1.0044x over previous
//
#include <hip/hip_runtime.h>
#include <math.h>

// TD(lambda) backward scan as a parallel suffix scan of affine maps.
// ret[t] = b[t] + a[t]*ret[t+1],  a[t]=g*(1-d)*lam[t],  b[t]=r[t]+g*(1-d)*(1-lam[t])*v[t+1]
//
// R5 (REVERTED): CU-temporal r/d loads -> 87us. nt is the fast load path.
// R8 (REVERTED): sc0/sc1 loads: FETCH bit-identical, read path 37% slower.
// R9 (WIN): temporal stores 63.4->60.3us. R10 (WIN): all reads on nt path via
//   aligned nt dwordx4 + neighbor-register recombine -> 56.5us.
// R11 (WIN, small): 512thr x C=4, one scan, one barrier -> ~54.5us.
//   Aggregate 4.93 TB/s = 78% of copy ceiling; reads 3.69 TB/s.
// R12: cross-row software pipeline. Block processes ROWS=4 rows; row k+1's
//   nt loads are issued BEFORE row k's scan/apply/store, so the ~1us of
//   non-load time per row (wave scan chain + barrier + store) overlaps the
//   next row's memory flight instead of idling the load pipe. s_barrier
//   does not drain vmcnt for register-destination loads, so the prefetch
//   survives the scan barrier. lam/gamma hoisted out of the row loop
//   (lam traffic /4). agg buffers parity-indexed (k&1) so iteration k+1's
//   writes never race iteration k's tail reads.

#define EPSV 1e-8f

typedef float f32x4 __attribute__((ext_vector_type(4)));

__global__ void precompute_lambda_kernel(const float* __restrict__ raw_gamma,
                                         const float* __restrict__ raw_lambd,
                                         float* __restrict__ lam, int S) {
    int t = blockIdx.x * blockDim.x + threadIdx.x;
    if (t < S) lam[t] = fmaxf(tanhf(raw_lambd[t]), EPSV);
    if (t == S) lam[S] = fmaxf(tanhf(raw_gamma[0]), EPSV);  // gamma stashed at lam[S]
}

// In-flight loads for one row. Loads are issued at construction; the v-quad
// recombine (shfl) happens at consumption.
struct RowLoads {
    f32x4 r, d, w;
    float vlast;
    const float* vbase;   // aligned base of the v window (vrow + t0 + 1 - s)
    int s;                // row-uniform misalignment 0..3
};

__device__ __forceinline__ RowLoads issue_row(const float* __restrict__ values,
                                              const float* __restrict__ rewards,
                                              const float* __restrict__ dones,
                                              int row, int S, int t0) {
    RowLoads L;
    const float* rrow = rewards + (size_t)row * S;
    const float* drow = dones   + (size_t)row * S;
    const float* vrow = values  + (size_t)row * (S + 1);
    L.r = __builtin_nontemporal_load(reinterpret_cast<const f32x4*>(rrow + t0));
    L.d = __builtin_nontemporal_load(reinterpret_cast<const f32x4*>(drow + t0));
    L.s = (int)(((uintptr_t)(vrow + 1) >> 2) & 3);
    L.vbase = vrow + t0 + 1 - L.s;
    L.w = __builtin_nontemporal_load(reinterpret_cast<const f32x4*>(L.vbase));
    L.vlast = vrow[S];
    return L;
}

// Recombine the aligned v-quad into the 4 floats starting at vp (= vbase+s).
// Spill-over floats come from the next lane's registers; lane 63 patches its
// tail with guarded scalar loads. s is wave-uniform.
__device__ __forceinline__ void recombine_v(const RowLoads& L, int lane,
                                            const float* __restrict__ hi,
                                            float vv[4]) {
    const f32x4 w = L.w;
    const int s = L.s;
    if (s == 0) { vv[0]=w[0]; vv[1]=w[1]; vv[2]=w[2]; vv[3]=w[3]; return; }
    float wn0 = __shfl_down(w[0], 1);
    float wn1 = __shfl_down(w[1], 1);
    float wn2 = __shfl_down(w[2], 1);
    if (lane == 63) {
        const float* p = L.vbase + 4;
        wn0 = (p + 0 < hi) ? p[0] : 0.0f;   // wn[j] only used for j < s
        wn1 = (p + 1 < hi) ? p[1] : 0.0f;
        wn2 = (p + 2 < hi) ? p[2] : 0.0f;
    }
    if (s == 1)      { vv[0]=w[1]; vv[1]=w[2]; vv[2]=w[3]; vv[3]=wn0; }
    else if (s == 2) { vv[0]=w[2]; vv[1]=w[3]; vv[2]=wn0; vv[3]=wn1; }
    else             { vv[0]=w[3]; vv[1]=wn0; vv[2]=wn1; vv[3]=wn2; }
}

// Block-wide suffix scan over NW*64 per-thread affine maps (A,Bc).
// Output: (Af,Bf) = exclusive suffix map of threads tid+1..NW*64-1.
// Contains exactly one __syncthreads.
template <int NW>
__device__ __forceinline__ void block_suffix_scan(
    float A, float Bc, float* aggAs, float* aggBs, int lane, int wave,
    float& Af, float& Bf)
{
    float Ai = A, Bi = Bc;
    #pragma unroll
    for (int off = 1; off < 64; off <<= 1) {
        float Ao = __shfl_down(Ai, off);
        float Bo = __shfl_down(Bi, off);
        if (lane + off < 64) { Bi = fmaf(Ai, Bo, Bi); Ai = Ai * Ao; }
    }
    float Ae = __shfl_down(Ai, 1);
    float Be = __shfl_down(Bi, 1);
    if (lane == 63) { Ae = 1.0f; Be = 0.0f; }

    if (lane == 0) { aggAs[wave] = Ai; aggBs[wave] = Bi; }
    __syncthreads();
    float TA = 1.0f, TB = 0.0f;          // tail = agg[wave+1] o ... o agg[NW-1]
    for (int w2 = wave + 1; w2 < NW; ++w2) {
        TB = fmaf(TA, aggBs[w2], TB);
        TA = TA * aggAs[w2];
    }
    Af = Ae * TA;
    Bf = fmaf(Ae, TB, Be);
}

__global__ __launch_bounds__(512) void lamret_kernel(
    const float* __restrict__ values,    // [B, S+1]
    const float* __restrict__ rewards,   // [B, S]
    const float* __restrict__ dones,     // [B, S]
    const float* __restrict__ raw_gamma, // [1]   (fallback path)
    const float* __restrict__ raw_lambd, // [S]   (fallback path)
    const float* __restrict__ lam_pre,   // [S+1] precomputed (or nullptr)
    float* __restrict__ out,             // [B, S]
    int S, long vtotal, int B)
{
    constexpr int ROWS = 4;
    __shared__ float aggA[2][8], aggB[2][8];

    const int tid  = threadIdx.x;
    const int lane = tid & 63;
    const int wave = tid >> 6;
    const int rbase = blockIdx.x * ROWS;
    const float* const hi = values + vtotal;

    float gamma;
    if (lam_pre) gamma = lam_pre[S];
    else         gamma = fmaxf(tanhf(raw_gamma[0]), EPSV);

    if (S == 2048) {
        // -------- fast path: 512 threads x C=4, ROWS-row software pipeline --------
        constexpr int C = 4;
        const int t0 = tid * C;

        // lam: row-invariant, loaded once
        float lm[C];
        if (lam_pre) {
            f32x4 l = *reinterpret_cast<const f32x4*>(lam_pre + t0);
            #pragma unroll
            for (int i = 0; i < C; ++i) lm[i] = l[i];
        } else {
            #pragma unroll
            for (int i = 0; i < C; ++i) lm[i] = fmaxf(tanhf(raw_lambd[t0 + i]), EPSV);
        }

        RowLoads cur;
        if (rbase < B) cur = issue_row(values, rewards, dones, rbase, S, t0);

        #pragma unroll
        for (int k = 0; k < ROWS; ++k) {
            const int row = rbase + k;
            const bool valid = (row < B);

            // ---- consume row k's loads into affine coefficients
            float a[C], b[C];
            if (valid) {
                float vv[C];
                recombine_v(cur, lane, hi, vv);
                #pragma unroll
                for (int i = 0; i < C; ++i) {
                    float g1d = gamma * (1.0f - cur.d[i]);
                    a[i] = g1d * lm[i];
                    b[i] = fmaf(g1d * (1.0f - lm[i]), vv[i], cur.r[i]);
                }
            } else {
                #pragma unroll
                for (int i = 0; i < C; ++i) { a[i] = 1.0f; b[i] = 0.0f; }
            }
            const float vlast = cur.vlast;

            // ---- issue row k+1's loads BEFORE the scan/store of row k
            RowLoads nxt;
            if (k + 1 < ROWS && row + 1 < B)
                nxt = issue_row(values, rewards, dones, row + 1, S, t0);

            // ---- local composition
            float A = 1.0f, Bc = 0.0f;
            #pragma unroll
            for (int i = C - 1; i >= 0; --i) {
                Bc = fmaf(a[i], Bc, b[i]);
                A  = a[i] * A;
            }

            // ---- single block scan (one barrier); parity-indexed agg
            float Af, Bf;
            block_suffix_scan<8>(A, Bc, aggA[k & 1], aggB[k & 1], lane, wave, Af, Bf);
            float x = fmaf(Af, vlast, Bf);

            // ---- backward apply + temporal store
            if (valid) {
                f32x4 o;
                #pragma unroll
                for (int i = C - 1; i >= 0; --i) {
                    x = fmaf(a[i], x, b[i]);
                    o[i] = x;
                }
                *reinterpret_cast<f32x4*>(out + (size_t)row * S + t0) = o;
            }
            cur = nxt;
        }
    } else {
        // -------- generic path: C=8 scalar per row, same ROWS loop --------
        constexpr int C = 8;
        const int t0 = tid * C;
        for (int k = 0; k < ROWS; ++k) {
            const int row = rbase + k;
            const bool valid = (row < B);
            float a[C], b[C];
            float vlast = 0.0f;
            if (valid) {
                const float* rrow = rewards + (size_t)row * S;
                const float* drow = dones   + (size_t)row * S;
                const float* vrow = values  + (size_t)row * (S + 1);
                vlast = vrow[S];
                #pragma unroll
                for (int i = 0; i < C; ++i) {
                    int t = t0 + i;
                    if (t < S) {
                        float lmv = lam_pre ? lam_pre[t] : fmaxf(tanhf(raw_lambd[t]), EPSV);
                        float g1d = gamma * (1.0f - drow[t]);
                        a[i] = g1d * lmv;
                        b[i] = fmaf(g1d * (1.0f - lmv), vrow[t + 1], rrow[t]);
                    } else { a[i] = 1.0f; b[i] = 0.0f; }
                }
            } else {
                #pragma unroll
                for (int i = 0; i < C; ++i) { a[i] = 1.0f; b[i] = 0.0f; }
            }
            float A = 1.0f, Bc = 0.0f;
            #pragma unroll
            for (int i = C - 1; i >= 0; --i) {
                Bc = fmaf(a[i], Bc, b[i]);
                A  = a[i] * A;
            }
            float Af, Bf;
            block_suffix_scan<8>(A, Bc, aggA[k & 1], aggB[k & 1], lane, wave, Af, Bf);
            float x = fmaf(Af, vlast, Bf);
            if (valid) {
                float* orow = out + (size_t)row * S;
                #pragma unroll
                for (int i = C - 1; i >= 0; --i) {
                    x = fmaf(a[i], x, b[i]);
                    if (t0 + i < S) orow[t0 + i] = x;
                }
            }
        }
    }
}

extern "C" void kernel_launch(void* const* d_in, const int* in_sizes, int n_in,
                              void* d_out, int out_size, void* d_ws, size_t ws_size,
                              hipStream_t stream) {
    const float* values    = (const float*)d_in[0];
    const float* rewards   = (const float*)d_in[1];
    const float* dones     = (const float*)d_in[2];
    const float* raw_gamma = (const float*)d_in[3];
    const float* raw_lambd = (const float*)d_in[4];
    float* out = (float*)d_out;

    const int S = in_sizes[4];            // raw_lambd length
    const int B = in_sizes[1] / S;        // rewards = B*S
    const long vtotal = in_sizes[0];      // B*(S+1)

    float* lam_pre = nullptr;
    if (ws_size >= (size_t)(S + 1) * sizeof(float)) {
        lam_pre = (float*)d_ws;
        int nthr = 256;
        int nblk = (S + 1 + nthr - 1) / nthr;
        precompute_lambda_kernel<<<nblk, nthr, 0, stream>>>(raw_gamma, raw_lambd, lam_pre, S);
    }

    // 4 rows per block; 512 threads * 4 steps = 2048 timesteps per row
    const int ROWS = 4;
    int nblk = (B + ROWS - 1) / ROWS;
    lamret_kernel<<<nblk, 512, 0, stream>>>(values, rewards, dones,
                                            raw_gamma, raw_lambd, lam_pre, out,
                                            S, vtotal, B);
}